// Round 1
// baseline (2616.320 us; speedup 1.0000x reference)
//
#include <hip/hip_runtime.h>
#include <hip/hip_bf16.h>
#include <math.h>

#define M_D    120
#define N_HEADS 8
#define DH     15
#define MOD_T  201
#define TABLE_MASK 0xFFFFFu

// ws float layout
#define WS_TQS 0          // 201*120, prescaled by inv_s
#define WS_TKS 24120      // 201*120, prescaled by inv_s
#define WS_TV  48240      // 201*120
#define WS_S11 72360      // 201*8

__device__ __forceinline__ float bf_lo(uint32_t d) { return __uint_as_float(d << 16); }
__device__ __forceinline__ float bf_hi(uint32_t d) { return __uint_as_float(d & 0xffff0000u); }

// ---- precompute time-token tables: TQ/TK/TV[t] = temb[t]@W + b, S11[t][h] ----
__global__ void precomp_time(const float* __restrict__ temb,
                             const float* __restrict__ Wq, const float* __restrict__ bq,
                             const float* __restrict__ Wk, const float* __restrict__ bk,
                             const float* __restrict__ Wv, const float* __restrict__ bv,
                             float* __restrict__ ws) {
  const float inv_s = 1.0f / sqrtf(15.0f);
  const int t = blockIdx.x;
  const int j = threadIdx.x;
  __shared__ float lq[M_D], lk[M_D];
  if (j < M_D) {
    float q = bq[j], k = bk[j], v = bv[j];
    const float* te = temb + t * M_D;
    for (int i = 0; i < M_D; ++i) {
      float x = te[i];
      q = fmaf(x, Wq[i * M_D + j], q);
      k = fmaf(x, Wk[i * M_D + j], k);
      v = fmaf(x, Wv[i * M_D + j], v);
    }
    lq[j] = q; lk[j] = k;
    ws[WS_TQS + t * M_D + j] = q * inv_s;
    ws[WS_TKS + t * M_D + j] = k * inv_s;
    ws[WS_TV  + t * M_D + j] = v;
  }
  __syncthreads();
  if (j < N_HEADS) {
    float s = 0.f;
    #pragma unroll
    for (int m_ = 0; m_ < DH; ++m_) s += lq[j * DH + m_] * lk[j * DH + m_];
    ws[WS_S11 + t * 8 + j] = s * inv_s;
  }
}

// ---- fused main: wave-per-point ----
__launch_bounds__(512, 1)
__global__ void fused_main(const float* __restrict__ qpts, const int* __restrict__ qtimes,
                           const float* __restrict__ dyn,  const int* __restrict__ hbuf,
                           const float* __restrict__ Wq, const float* __restrict__ bq,
                           const float* __restrict__ Wk, const float* __restrict__ bk,
                           const float* __restrict__ Wv, const float* __restrict__ bv,
                           const float* __restrict__ Wo, const float* __restrict__ bo,
                           const float* __restrict__ ws, float* __restrict__ out, int M) {
  // LDS: 4 weight mats as bf16 column-pairs, i-pair interleaved for ds_read_b64.
  // dword(mat, i, l) holds {lo16 = bf16(W[i][l]), hi16 = bf16(W[i][l+64])} at
  // index (i>>1)*128 + 2*l + (i&1).  7680 dwords per matrix.
  __shared__ __align__(16) uint32_t wlds[4 * 7680];   // 120 KiB
  __shared__ __align__(16) float fqk[8 * 256];        // per-wave scratch: feat/q/k/c + alpha/beta

  const int tid  = threadIdx.x;
  const int lane = tid & 63;
  const int wv   = tid >> 6;

  auto stage = [&](const float* Wg, uint32_t* dst) {
    for (int r = tid; r < 7680; r += 512) {
      int i = r >> 6, l = r & 63;
      float lo = Wg[i * M_D + l];
      float hi = (l < 56) ? Wg[i * M_D + 64 + l] : 0.0f;
      dst[(i >> 1) * 128 + (l << 1) + (i & 1)] =
          (__float_as_uint(lo) >> 16) | (__float_as_uint(hi) & 0xffff0000u);
    }
  };
  stage(Wq, wlds);
  stage(Wk, wlds + 7680);
  stage(Wv, wlds + 2 * 7680);
  stage(Wo, wlds + 3 * 7680);
  __syncthreads();

  const uint32_t* wq = wlds;
  const uint32_t* wk = wlds + 7680;
  const uint32_t* wvm = wlds + 2 * 7680;
  const uint32_t* wo = wlds + 3 * 7680;
  float* fbuf = fqk + wv * 256;          // [0..119] feat/c, [120..239] k, [240..255] alpha/beta

  const float* TQs = ws + WS_TQS;
  const float* TKs = ws + WS_TKS;
  const float* TV  = ws + WS_TV;
  const float* S11 = ws + WS_S11;
  const float inv_s = 1.0f / sqrtf(15.0f);

  // per-lane biases (element lane and lane+64), hoisted out of the point loop
  float bq0 = bq[lane], bk0 = bk[lane], bv0 = bv[lane], bo0 = bo[lane];
  float bq1 = 0.f, bk1 = 0.f, bv1 = 0.f, bo1 = 0.f;
  if (lane < 56) { bq1 = bq[64 + lane]; bk1 = bk[64 + lane]; bv1 = bv[64 + lane]; bo1 = bo[64 + lane]; }

  const int gw = blockIdx.x * 8 + wv;
  const int nw = gridDim.x * 8;
  for (int p = gw; p < M; p += nw) {
    float px = qpts[3 * p], py = qpts[3 * p + 1], pz = qpts[3 * p + 2];
    int tm = qtimes[p] % MOD_T;
    float gx = px / 0.1f, gy = py / 0.1f, gz = pz / 0.1f;
    float fx = floorf(gx), fy = floorf(gy), fz = floorf(gz);
    float rx = gx - fx, ry = gy - fy, rz = gz - fz;
    int bx = (int)fx, by = (int)fy, bz = (int)fz;

    // this lane's corner (lanes 8..63 replicate corners 0..7)
    int c = lane & 7;
    int ox = c & 1, oy = (c >> 1) & 1, oz = (c >> 2) & 1;
    uint32_t hh = (uint32_t)(bx + ox) * 73856093u + (uint32_t)(by + oy) * 19349669u +
                  (uint32_t)(bz + oz) * 83492791u;
    int vidx = hbuf[hh & TABLE_MASK];
    float wx = ox ? rx : 1.0f - rx;
    float wy = oy ? ry : 1.0f - ry;
    float wz = oz ? rz : 1.0f - rz;
    float wgt = wx * wy * wz;

    // trilinear gather: lane holds feat elements (lane) and (lane+64)
    float a0 = 0.f, a1 = 0.f;
    #pragma unroll
    for (int cc = 0; cc < 8; ++cc) {
      int vc   = __builtin_amdgcn_readlane(vidx, cc);
      float wc = __uint_as_float(__builtin_amdgcn_readlane(__float_as_uint(wgt), cc));
      if (vc >= 0) {
        const float* fr = dyn + (long)vc * M_D;
        a0 = fmaf(fr[lane], wc, a0);
        if (lane < 56) a1 = fmaf(fr[64 + lane], wc, a1);
      }
    }
    fbuf[lane] = a0;
    if (lane < 56) fbuf[64 + lane] = a1;

    // q,k,v = feat @ W + b   (lane computes output elems lane and lane+64)
    float q0 = bq0, q1 = bq1, k0 = bk0, k1 = bk1, v0 = bv0, v1 = bv1;
    #pragma unroll 4
    for (int i2 = 0; i2 < 60; ++i2) {
      float2 f2 = *(const float2*)(fbuf + 2 * i2);              // broadcast
      uint2 dq = *(const uint2*)(wq  + i2 * 128 + 2 * lane);
      uint2 dk = *(const uint2*)(wk  + i2 * 128 + 2 * lane);
      uint2 dv = *(const uint2*)(wvm + i2 * 128 + 2 * lane);
      q0 = fmaf(f2.x, bf_lo(dq.x), q0); q1 = fmaf(f2.x, bf_hi(dq.x), q1);
      q0 = fmaf(f2.y, bf_lo(dq.y), q0); q1 = fmaf(f2.y, bf_hi(dq.y), q1);
      k0 = fmaf(f2.x, bf_lo(dk.x), k0); k1 = fmaf(f2.x, bf_hi(dk.x), k1);
      k0 = fmaf(f2.y, bf_lo(dk.y), k0); k1 = fmaf(f2.y, bf_hi(dk.y), k1);
      v0 = fmaf(f2.x, bf_lo(dv.x), v0); v1 = fmaf(f2.x, bf_hi(dv.x), v1);
      v0 = fmaf(f2.y, bf_lo(dv.y), v0); v1 = fmaf(f2.y, bf_hi(dv.y), v1);
    }

    // stash q,k for per-head score dots (feat no longer needed)
    fbuf[lane] = q0;        if (lane < 56) fbuf[64 + lane]  = q1;
    fbuf[120 + lane] = k0;  if (lane < 56) fbuf[184 + lane] = k1;

    if (lane < 8) {
      int h = lane;
      const float* tks = TKs + tm * M_D + h * DH;
      const float* tqs = TQs + tm * M_D + h * DH;
      float s00 = 0.f, s01 = 0.f, s10 = 0.f;
      #pragma unroll
      for (int m_ = 0; m_ < DH; ++m_) {
        float qm = fbuf[h * DH + m_];
        float km = fbuf[120 + h * DH + m_];
        s00 = fmaf(qm, km, s00);
        s01 = fmaf(qm, tks[m_], s01);
        s10 = fmaf(tqs[m_], km, s10);
      }
      s00 *= inv_s;
      float s11 = S11[tm * 8 + h];
      float m0 = fmaxf(s00, s01), m1 = fmaxf(s10, s11);
      float e00 = expf(s00 - m0), e01 = expf(s01 - m0);
      float e10 = expf(s10 - m1), e11 = expf(s11 - m1);
      float r0 = 1.f / (e00 + e01), r1 = 1.f / (e10 + e11);
      fbuf[240 + h] = 0.5f * (e00 * r0 + e10 * r1);   // alpha_h (coeff on v_feat)
      fbuf[248 + h] = 0.5f * (e01 * r0 + e11 * r1);   // beta_h  (coeff on v_time)
    }

    // combined = alpha .* v_feat + beta .* v_time  (segment-wise per head)
    int h0 = lane / 15;
    float c0 = fbuf[240 + h0] * v0 + fbuf[248 + h0] * TV[tm * M_D + lane];
    fbuf[lane] = c0;
    if (lane < 56) {
      int h1 = (64 + lane) / 15;
      float c1 = fbuf[240 + h1] * v1 + fbuf[248 + h1] * TV[tm * M_D + 64 + lane];
      fbuf[64 + lane] = c1;
    }

    // out = combined @ Wo + bo
    float o0 = bo0, o1 = bo1;
    #pragma unroll 4
    for (int i2 = 0; i2 < 60; ++i2) {
      float2 f2 = *(const float2*)(fbuf + 2 * i2);
      uint2 dw = *(const uint2*)(wo + i2 * 128 + 2 * lane);
      o0 = fmaf(f2.x, bf_lo(dw.x), o0); o1 = fmaf(f2.x, bf_hi(dw.x), o1);
      o0 = fmaf(f2.y, bf_lo(dw.y), o0); o1 = fmaf(f2.y, bf_hi(dw.y), o1);
    }
    out[(long)p * M_D + lane] = o0;
    if (lane < 56) out[(long)p * M_D + 64 + lane] = o1;
  }
}

extern "C" void kernel_launch(void* const* d_in, const int* in_sizes, int n_in,
                              void* d_out, int out_size, void* d_ws, size_t ws_size,
                              hipStream_t stream) {
  const float* qpts  = (const float*)d_in[0];
  const int*   qtimes= (const int*)d_in[1];
  const float* dyn   = (const float*)d_in[2];
  const float* temb  = (const float*)d_in[3];
  const int*   hbuf  = (const int*)d_in[4];
  const float* Wq = (const float*)d_in[5];
  const float* bq = (const float*)d_in[6];
  const float* Wk = (const float*)d_in[7];
  const float* bk = (const float*)d_in[8];
  const float* Wv = (const float*)d_in[9];
  const float* bv = (const float*)d_in[10];
  const float* Wo = (const float*)d_in[11];
  const float* bo = (const float*)d_in[12];
  float* out = (float*)d_out;
  float* ws  = (float*)d_ws;
  const int M = in_sizes[1];

  hipLaunchKernelGGL(precomp_time, dim3(MOD_T), dim3(128), 0, stream,
                     temb, Wq, bq, Wk, bk, Wv, bv, ws);
  hipLaunchKernelGGL(fused_main, dim3(512), dim3(512), 0, stream,
                     qpts, qtimes, dyn, hbuf, Wq, bq, Wk, bk, Wv, bv, Wo, bo, ws, out, M);
}

// Round 3
// 1118.997 us; speedup vs baseline: 2.3381x; 2.3381x over previous
//
#include <hip/hip_runtime.h>
#include <math.h>

#define M_D   120
#define MOD_T 201
#define TABLE_MASK 0xFFFFFu
#define INV_S 0.25819888974716115f   // 1/sqrt(15)

// ws layout (floats): S11[201*8] @0 ; TV'[201*128] @1608 ; TQK'[201*128] (u32 f16x2) @27336
#define WS_TV  1608
#define WS_TQK 27336

typedef float    f32x4 __attribute__((ext_vector_type(4)));
typedef uint32_t u32x4 __attribute__((ext_vector_type(4)));
typedef __fp16   f16x2v __attribute__((ext_vector_type(2)));
typedef __fp16   f16x8 __attribute__((ext_vector_type(8)));

union PK2 { f16x2v h; uint32_t u; };
union BFrag { f16x8 v; f16x2v h2[4]; uint32_t u[4]; };

// ---------- precompute padded time-token tables ----------
__global__ void precomp_time(const float* __restrict__ temb,
                             const float* __restrict__ Wq, const float* __restrict__ bq,
                             const float* __restrict__ Wk, const float* __restrict__ bk,
                             const float* __restrict__ Wv, const float* __restrict__ bv,
                             float* __restrict__ ws) {
  const int t = blockIdx.x, np = threadIdx.x;      // np = padded col n' in [0,128)
  const int h = np >> 4, m = np & 15;
  const bool valid = (m < 15);
  const int col = h * 15 + m;
  __shared__ float lq[128], lk[128];
  float q = 0.f, k = 0.f, v = 0.f;
  if (valid) {
    q = bq[col]; k = bk[col]; v = bv[col];
    const float* te = temb + t * M_D;
    for (int i = 0; i < M_D; ++i) {
      float x = te[i];
      q = fmaf(x, Wq[i * M_D + col], q);
      k = fmaf(x, Wk[i * M_D + col], k);
      v = fmaf(x, Wv[i * M_D + col], v);
    }
  }
  lq[np] = q; lk[np] = k;
  ws[WS_TV + t * 128 + np] = v;                    // 0 on pad cols
  PK2 pk; pk.h[0] = (__fp16)(q * INV_S); pk.h[1] = (__fp16)k;
  ((uint32_t*)ws)[WS_TQK + t * 128 + np] = pk.u;   // lo=tq*inv_s, hi=tk
  __syncthreads();
  if (np < 8) {
    float s = 0.f;
    #pragma unroll
    for (int mm = 0; mm < 15; ++mm) s += lq[np * 16 + mm] * lk[np * 16 + mm];
    ws[t * 8 + np] = s * INV_S;                    // S11
  }
}

// ---------- fused main: wave = 16 points, transposed MFMA ----------
__launch_bounds__(512, 2)
__global__ void fused_main(const float* __restrict__ qpts, const int* __restrict__ qtimes,
                           const float* __restrict__ dyn,  const int* __restrict__ hbuf,
                           const float* __restrict__ Wq, const float* __restrict__ bq,
                           const float* __restrict__ Wk, const float* __restrict__ bk,
                           const float* __restrict__ Wv, const float* __restrict__ bv,
                           const float* __restrict__ Wo, const float* __restrict__ bo,
                           const float* __restrict__ ws, float* __restrict__ out, int M) {
  // Weights in A-fragment order, f16: dword idx = mat*8192 + nt*1024 + kk*256 + l*4 + d
  // A[row = 16nt + (l&15)][k = 32kk + (l>>4)*8 + 2d + {0,1}]
  __shared__ __align__(16) uint32_t wlds[4 * 8192];   // 128 KiB

  const int tid = threadIdx.x;
  // ---- stage weights (once per block) ----
  for (int idx = tid; idx < 32768; idx += 512) {
    const int mat = idx >> 13, r = idx & 8191;
    const int nt = r >> 10, kk = (r >> 8) & 3, l = (r >> 2) & 63, d = r & 3;
    const int mm = l & 15;                 // row within tile
    const int i0 = kk * 32 + ((l >> 4) << 3) + 2 * d;
    float v0 = 0.f, v1 = 0.f;
    if (mat < 3) {
      // QKV: row n' = 16*nt + mm -> head nt, within-head mm (pad mm==15)
      const float* W = (mat == 0) ? Wq : (mat == 1) ? Wk : Wv;
      const float* b = (mat == 0) ? bq : (mat == 1) ? bk : bv;
      if (mm < 15) {
        const int col = nt * 15 + mm;
        const int ia = i0, ib = i0 + 1;
        v0 = (ia < 120) ? W[ia * M_D + col] : (ia == 120 ? b[col] : 0.f);
        v1 = (ib < 120) ? W[ib * M_D + col] : (ib == 120 ? b[col] : 0.f);
        if (mat == 0) { v0 *= INV_S; v1 *= INV_S; }
      }
    } else {
      // Wo: row = output n = 16*nt+mm (valid < 120); k index i' in padded comb space
      const int n = nt * 16 + mm;
      if (n < M_D) {
        #pragma unroll
        for (int e = 0; e < 2; ++e) {
          const int ip = i0 + e;
          const int hi = ip >> 4, mi = ip & 15;
          float vv = 0.f;
          if (mi < 15) vv = Wo[(hi * 15 + mi) * M_D + n];
          else if (ip == 15) vv = bo[n];           // bias slot k'=15
          if (e == 0) v0 = vv; else v1 = vv;
        }
      }
    }
    PK2 pk; pk.h[0] = (__fp16)v0; pk.h[1] = (__fp16)v1;
    wlds[idx] = pk.u;
  }
  __syncthreads();

  const int l = tid & 63, wv = tid >> 6;
  const int g = l >> 4, pl = l & 15, c0 = g << 2;
  const float* S11 = ws;
  const float* TVt = ws + WS_TV;
  const uint32_t* TQK = (const uint32_t*)ws + WS_TQK;

  const int T = (M + 15) >> 4;
  for (int tile = blockIdx.x * 8 + wv; tile < T; tile += gridDim.x * 8) {
    const int pid = (tile << 4) + pl;
    const int p = (pid < M) ? pid : (M - 1);

    // ---- point data ----
    const float px = qpts[3 * p], py = qpts[3 * p + 1], pz = qpts[3 * p + 2];
    const int tm = qtimes[p] % MOD_T;
    const float gx = px / 0.1f, gy = py / 0.1f, gz = pz / 0.1f;
    const float fx = floorf(gx), fy = floorf(gy), fz = floorf(gz);
    const float rx = gx - fx, ry = gy - fy, rz = gz - fz;
    const int bx = (int)fx, by = (int)fy, bz = (int)fz;

    // ---- trilinear hash gather into B-fragment slices ----
    // lane covers feat indices i = 32*kk + 8*g + j  (j 0..7)
    f32x4 accA[4] = {{0,0,0,0},{0,0,0,0},{0,0,0,0},{0,0,0,0}};
    f32x4 accB[4] = {{0,0,0,0},{0,0,0,0},{0,0,0,0},{0,0,0,0}};
    const int i0g = g * 8;
    #pragma unroll
    for (int c = 0; c < 8; ++c) {
      const int ox = c & 1, oy = (c >> 1) & 1, oz = c >> 2;
      const uint32_t hh = (uint32_t)(bx + ox) * 73856093u +
                          (uint32_t)(by + oy) * 19349669u +
                          (uint32_t)(bz + oz) * 83492791u;
      const int vc = hbuf[hh & TABLE_MASK];
      const float wc = (ox ? rx : 1.f - rx) * (oy ? ry : 1.f - ry) * (oz ? rz : 1.f - rz);
      if (vc >= 0) {
        const float* fr = dyn + (long)vc * M_D + i0g;
        #pragma unroll
        for (int kk = 0; kk < 4; ++kk) {
          if (kk < 3 || g < 3) {     // (kk==3,g==3) would read past row end
            f32x4 lo4 = *(const f32x4*)(fr + kk * 32);
            f32x4 hi4 = *(const f32x4*)(fr + kk * 32 + 4);
            accA[kk] += lo4 * wc;
            accB[kk] += hi4 * wc;
          }
        }
      }
    }
    if (g == 3) accA[3][0] = 1.0f;   // k=120 bias slot: feat[120] = 1

    // ---- pack B fragments (f16) ----
    BFrag bf[4];
    #pragma unroll
    for (int kk = 0; kk < 4; ++kk) {
      bf[kk].h2[0] = __builtin_amdgcn_cvt_pkrtz(accA[kk][0], accA[kk][1]);
      bf[kk].h2[1] = __builtin_amdgcn_cvt_pkrtz(accA[kk][2], accA[kk][3]);
      bf[kk].h2[2] = __builtin_amdgcn_cvt_pkrtz(accB[kk][0], accB[kk][1]);
      bf[kk].h2[3] = __builtin_amdgcn_cvt_pkrtz(accB[kk][2], accB[kk][3]);
    }

    // ---- time-token loads (hide under MFMA) ----
    f32x4 tvv[8]; u32x4 tqk[8]; float s11v[8];
    #pragma unroll
    for (int nt = 0; nt < 8; ++nt) {
      tvv[nt] = *(const f32x4*)(TVt + tm * 128 + nt * 16 + c0);
      tqk[nt] = *(const u32x4*)(TQK + tm * 128 + nt * 16 + c0);
      s11v[nt] = S11[tm * 8 + nt];
    }

    // ---- QKV GEMMs: D[n'][p], lane holds col p=pl, rows n' = 16nt+4g+r ----
    f32x4 aq[8], ak[8], av[8];
    #pragma unroll
    for (int nt = 0; nt < 8; ++nt) {
      f32x4 zq = {0,0,0,0}, zk = {0,0,0,0}, zv = {0,0,0,0};
      #pragma unroll
      for (int kk = 0; kk < 4; ++kk) {
        const int off = nt * 1024 + kk * 256 + l * 4;
        f16x8 a0 = *(const f16x8*)(wlds + off);
        f16x8 a1 = *(const f16x8*)(wlds + 8192 + off);
        f16x8 a2 = *(const f16x8*)(wlds + 16384 + off);
        zq = __builtin_amdgcn_mfma_f32_16x16x32_f16(a0, bf[kk].v, zq, 0, 0, 0);
        zk = __builtin_amdgcn_mfma_f32_16x16x32_f16(a1, bf[kk].v, zk, 0, 0, 0);
        zv = __builtin_amdgcn_mfma_f32_16x16x32_f16(a2, bf[kk].v, zv, 0, 0, 0);
      }
      aq[nt] = zq; ak[nt] = zk; av[nt] = zv;
    }

    // ---- scores + softmax, fully in-register (head h == nt) ----
    float a_[8], b_[8];
    #pragma unroll
    for (int nt = 0; nt < 8; ++nt) {
      float s00 = 0.f, s01 = 0.f, s10 = 0.f;
      #pragma unroll
      for (int r = 0; r < 4; ++r) {
        const float qv = aq[nt][r], kv = ak[nt][r];
        PK2 tt; tt.u = tqk[nt][r];
        const float tqs = (float)tt.h[0], tk = (float)tt.h[1];
        s00 = fmaf(qv, kv, s00);
        s01 = fmaf(qv, tk, s01);
        s10 = fmaf(tqs, kv, s10);
      }
      s00 += __shfl_xor(s00, 16); s00 += __shfl_xor(s00, 32);
      s01 += __shfl_xor(s01, 16); s01 += __shfl_xor(s01, 32);
      s10 += __shfl_xor(s10, 16); s10 += __shfl_xor(s10, 32);
      const float s11 = s11v[nt];
      const float m0 = fmaxf(s00, s01), m1 = fmaxf(s10, s11);
      const float e00 = __expf(s00 - m0), e01 = __expf(s01 - m0);
      const float e10 = __expf(s10 - m1), e11 = __expf(s11 - m1);
      const float r0 = 1.f / (e00 + e01), r1 = 1.f / (e10 + e11);
      a_[nt] = 0.5f * (e00 * r0 + e10 * r1);
      b_[nt] = 0.5f * (e01 * r0 + e11 * r1);
    }

    // ---- combined = alpha*V + beta*TV (padded space), pack f16 ----
    uint32_t cdw[8][2];
    #pragma unroll
    for (int nt = 0; nt < 8; ++nt) {
      f32x4 cv;
      #pragma unroll
      for (int r = 0; r < 4; ++r) cv[r] = a_[nt] * av[nt][r] + b_[nt] * tvv[nt][r];
      if (nt == 0 && g == 3) cv[3] = 1.0f;   // comb[p][15] = 1 -> O bias row
      PK2 p0, p1;
      p0.h = __builtin_amdgcn_cvt_pkrtz(cv[0], cv[1]);
      p1.h = __builtin_amdgcn_cvt_pkrtz(cv[2], cv[3]);
      cdw[nt][0] = p0.u; cdw[nt][1] = p1.u;
    }

    // ---- redistribute comb (D-layout) -> B-fragments for O GEMM ----
    // B dword[kk][d] = cdw[2kk + (g>>1)][d&1] from lane (pl, gA=2(g&1)+(d>>1))
    const int src0 = pl | ((g & 1) << 5);
    const int src1 = src0 + 16;
    const bool hsel = (g >= 2);
    BFrag bco[4];
    #pragma unroll
    for (int kk = 0; kk < 4; ++kk) {
      #pragma unroll
      for (int d = 0; d < 4; ++d) {
        const int s = (d >= 2) ? src1 : src0;
        const int vlo = __shfl((int)cdw[2 * kk][d & 1], s, 64);
        const int vhi = __shfl((int)cdw[2 * kk + 1][d & 1], s, 64);
        bco[kk].u[d] = hsel ? (uint32_t)vhi : (uint32_t)vlo;
      }
    }

    // ---- O GEMM + store ----
    float* orow = out + (long)pid * M_D;
    #pragma unroll
    for (int nt = 0; nt < 8; ++nt) {
      f32x4 zo = {0,0,0,0};
      #pragma unroll
      for (int kk = 0; kk < 4; ++kk) {
        f16x8 a3 = *(const f16x8*)(wlds + 24576 + nt * 1024 + kk * 256 + l * 4);
        zo = __builtin_amdgcn_mfma_f32_16x16x32_f16(a3, bco[kk].v, zo, 0, 0, 0);
      }
      if (pid < M && (nt < 7 || g < 2))      // n = 16nt+4g+r < 120
        *(f32x4*)(orow + nt * 16 + c0) = zo;
    }
  }
}

extern "C" void kernel_launch(void* const* d_in, const int* in_sizes, int n_in,
                              void* d_out, int out_size, void* d_ws, size_t ws_size,
                              hipStream_t stream) {
  const float* qpts   = (const float*)d_in[0];
  const int*   qtimes = (const int*)d_in[1];
  const float* dyn    = (const float*)d_in[2];
  const float* temb   = (const float*)d_in[3];
  const int*   hbuf   = (const int*)d_in[4];
  const float* Wq = (const float*)d_in[5];
  const float* bq = (const float*)d_in[6];
  const float* Wk = (const float*)d_in[7];
  const float* bk = (const float*)d_in[8];
  const float* Wv = (const float*)d_in[9];
  const float* bv = (const float*)d_in[10];
  const float* Wo = (const float*)d_in[11];
  const float* bo = (const float*)d_in[12];
  float* out = (float*)d_out;
  float* ws  = (float*)d_ws;
  const int M = in_sizes[1];

  hipLaunchKernelGGL(precomp_time, dim3(MOD_T), dim3(128), 0, stream,
                     temb, Wq, bq, Wk, bk, Wv, bv, ws);
  hipLaunchKernelGGL(fused_main, dim3(256), dim3(512), 0, stream,
                     qpts, qtimes, dyn, hbuf, Wq, bq, Wk, bk, Wv, bv, Wo, bo, ws, out, M);
}